// Round 8
// baseline (640.288 us; speedup 1.0000x reference)
//
#include <hip/hip_runtime.h>
#include <hip/hip_bf16.h>
#include <math.h>

#define NPOS 131072   // N
#define NF   69       // FEAT
#define NMRG 32768    // N/4
#define TILE 512
#define TPS  256      // NPOS/TILE
#define NSORT 4
#define EPT  8
#define CSTR 66

typedef __attribute__((ext_vector_type(8))) short short8;
typedef __bf16 bf16x8 __attribute__((ext_vector_type(8)));
typedef __attribute__((ext_vector_type(4))) float f32x4;

static __device__ inline bf16x8 as_bf16x8(short8 v){ union{short8 s; bf16x8 b;} u; u.s=v; return u.b; }
static __device__ inline short f2bf(float x){ __hip_bfloat16 h = __float2bfloat16(x); return *(short*)&h; }
static __device__ inline float bf2f(short s){ return __uint_as_float(((unsigned)(unsigned short)s)<<16); }

// async global->LDS, 16B per lane; LDS dest = wave-uniform base + lane*16 (linear)
static __device__ inline void gld16(const short* g, short* l){
  __builtin_amdgcn_global_load_lds(
      (const __attribute__((address_space(1))) unsigned int*)g,
      (__attribute__((address_space(3))) unsigned int*)l, 16, 0, 0);
}

// ---------------- stable argsort: LSD radix, 4x8-bit ----------------
__global__ void k_make_keys(const float* __restrict__ inp, unsigned* __restrict__ kA,
                            unsigned* __restrict__ vA){
  unsigned t = blockIdx.x*256u + threadIdx.x;
  unsigned s = t >> 17, i = t & (NPOS-1u);
  unsigned b = s >> 1, ch = 3u + (s & 1u);
  float x = inp[((size_t)b*NPOS + i)*NF + ch];
  unsigned u = __float_as_uint(x);
  u = (u & 0x80000000u) ? ~u : (u | 0x80000000u);
  kA[t] = u; vA[t] = i;
}

__global__ __launch_bounds__(256) void k_hist(const unsigned* __restrict__ src,
                                              unsigned* __restrict__ hist, int shift){
  __shared__ unsigned h[256];
  int tid = threadIdx.x;
  h[tid] = 0u; __syncthreads();
  int s = blockIdx.x >> 8, tile = blockIdx.x & 255;
  const unsigned* ks = src + (size_t)s*NPOS + (size_t)tile*TILE;
  #pragma unroll
  for (int r = 0; r < TILE/256; ++r){
    unsigned d = (ks[r*256 + tid] >> shift) & 255u;
    atomicAdd(&h[d], 1u);
  }
  __syncthreads();
  hist[s*65536 + tid*TPS + tile] = h[tid];          // [s][bin][tile]
}

__global__ __launch_bounds__(256) void k_scan(unsigned* __restrict__ hist){
  __shared__ unsigned tot[256];
  int tid = threadIdx.x; int s = blockIdx.x;
  unsigned* g = hist + s*65536;
  unsigned sum = 0;
  for (int q = 0; q < TPS; ++q) sum += g[tid*TPS + q];
  tot[tid] = sum;
  __syncthreads();
  if (tid == 0){
    unsigned run = 0;
    for (int t = 0; t < 256; ++t){ unsigned tmp = tot[t]; tot[t] = run; run += tmp; }
  }
  __syncthreads();
  unsigned run = tot[tid];
  for (int q = 0; q < TPS; ++q){ unsigned tmp = g[tid*TPS+q]; g[tid*TPS+q] = run; run += tmp; }
}

__global__ __launch_bounds__(64) void k_scatter(const unsigned* __restrict__ srcK,
    const unsigned* __restrict__ srcV, unsigned* __restrict__ dstK, unsigned* __restrict__ dstV,
    const unsigned* __restrict__ off, int shift){
  __shared__ unsigned short cnt[256*CSTR];          // [digit][thread], stride 66 -> banks rotate
  int tid = threadIdx.x;
  short8* cz = (short8*)cnt;
  short8 z = {0,0,0,0,0,0,0,0};
  for (int idx = tid; idx < 256*CSTR/8; idx += 64) cz[idx] = z;
  __syncthreads();
  int s = blockIdx.x >> 8, tile = blockIdx.x & 255;
  const unsigned* ks = srcK + (size_t)s*NPOS + (size_t)tile*TILE;
  const unsigned* vs = srcV + (size_t)s*NPOS + (size_t)tile*TILE;
  unsigned k8[EPT], v8[EPT];
  #pragma unroll
  for (int r = 0; r < EPT; ++r){                    // thread t owns elems [t*8, t*8+8)
    k8[r] = ks[tid*EPT + r];
    v8[r] = vs[tid*EPT + r];
    unsigned d = (k8[r] >> shift) & 255u;
    cnt[d*CSTR + tid]++;
  }
  __syncthreads();
  #pragma unroll
  for (int dd = 0; dd < 4; ++dd){                   // exclusive scan over threads per digit
    int d = tid + dd*64;
    unsigned run = 0;
    for (int t = 0; t < 64; ++t){ unsigned tmp = cnt[d*CSTR + t]; cnt[d*CSTR + t] = (unsigned short)run; run += tmp; }
  }
  __syncthreads();
  const unsigned* ob = off + s*65536;
  #pragma unroll
  for (int r = 0; r < EPT; ++r){                    // stable scatter
    unsigned d = (k8[r] >> shift) & 255u;
    unsigned rk = cnt[d*CSTR + tid];
    cnt[d*CSTR + tid] = (unsigned short)(rk + 1u);
    unsigned pos = ob[d*TPS + tile] + rk;
    dstK[(size_t)s*NPOS + pos] = k8[r];
    dstV[(size_t)s*NPOS + pos] = v8[r];
  }
}

// ---------------- gather ----------------
// XA layout  [224]: [conv0out 0..127][x0 128..196][pad]
// Xcat layout[272]: [conv1out 0..127][F 128..131][x0 132..200][g 201..269][0 270..271]
__global__ __launch_bounds__(256) void k_gath(const float* __restrict__ inp,
    const unsigned* __restrict__ P1, const unsigned* __restrict__ P0,
    short* __restrict__ XA, short* __restrict__ Xcat, int b){
  int t = blockIdx.x*256 + threadIdx.x;   // NPOS*128
  int i = t >> 7, c = t & 127;
  if (c < 69){
    short s1 = f2bf(inp[((size_t)b*NPOS + P1[i])*NF + c]);
    XA[(size_t)i*224 + 128 + c] = s1;
    Xcat[(size_t)i*272 + 132 + c] = s1;
    Xcat[(size_t)i*272 + 201 + c] = f2bf(inp[((size_t)b*NPOS + P0[i])*NF + c]);
  } else if (c == 69){
    Xcat[(size_t)i*272 + 270] = 0;
    Xcat[(size_t)i*272 + 271] = 0;
  }
}

// ---------------- weight prep: lane-major [wv][q][ksub][ni][lane][8] ----------------
// value = W[tap = q/KC][ch = (q%KC)*64 + ksub*32 + (lane>>4)*8 + e][nn = wv*32+ni*16+(lane&15)]
__global__ void k_prepB(const float* __restrict__ w, short* __restrict__ out,
                        int KC, int NQ, int mode, int total){
  int t = blockIdx.x*256 + threadIdx.x;   // one 16B unit (8 weights) per thread
  if (t >= total) return;
  int lane = t & 63, ni = (t>>6) & 1, ksub = (t>>7) & 1;
  int rest = t >> 8;
  int q = rest % NQ;   // (tap, chunk) linearized
  int wv = rest / NQ;
  int tap = q / KC, cc = q - tap*KC;
  int nn = wv*32 + ni*16 + (lane & 15);
  int chb = cc*64 + ksub*32 + ((lane >> 4) & 3)*8;
  short o[8];
  #pragma unroll
  for (int e = 0; e < 8; ++e){
    int ch = chb + e;
    float val = 0.f;
    if (mode == 0){ if (ch < 69)  val = w[((size_t)tap*69  + ch)*128 + nn]; }
    else if (mode == 1){
      if (ch < 128)      val = w[((size_t)tap*197 + 69 + ch)*128 + nn];
      else if (ch < 197) val = w[((size_t)tap*197 + ch - 128)*128 + nn];
    }
    else if (mode == 2){ if (ch < 128) val = w[((size_t)tap*128 + ch)*128 + nn]; }
    else {
      int tm = ch / 272, cm = ch - tm*272;
      int orig = -1;
      if (cm < 128)      orig = 73 + cm;
      else if (cm < 201) orig = cm - 128;
      else if (cm < 270) orig = cm;
      if (orig >= 0) val = w[((size_t)tm*270 + orig)*128 + nn];
    }
    o[e] = f2bf(val);
  }
  *(short8*)(out + (size_t)t*8) = *(short8*)o;
}

__global__ void k_prepWf(const float* __restrict__ wf, float* __restrict__ out){
  int t = blockIdx.x*256 + threadIdx.x;   // 272*4
  if (t >= 1088) return;
  int c = t >> 2, q = t & 3;
  float v = 0.f;
  if (c < 128)                 v = wf[(69 + c)*4 + q];
  else if (c >= 132 && c < 201) v = wf[(c - 132)*4 + q];
  else if (c >= 201 && c < 270) v = wf[(197 + c - 201)*4 + q];
  out[t] = v;
}

#define OSTR 132   // f32 epilogue stride: 132 dwords = 528B, 16B-aligned, banks spread

// ---------------- MFMA conv3: 4-deep B-prefetch ring, barrier-free K-loop ----------------
template<int CPAD>
__global__ __launch_bounds__(256) void k_conv3p(
    const short* __restrict__ src, int sstride, int coff, int cin,
    const short* __restrict__ wB, const float* __restrict__ bias,
    short* __restrict__ dst, int dstride, int n)
{
  constexpr int KC = CPAD/64;          // K-chunks of 64 per tap
  constexpr int NSTEP2 = 3*KC*2;       // (tap,chunk,ksub) linear steps
  constexpr int PF = 4;                // B prefetch depth
  constexpr int ASTR = CPAD + 8;       // dword stride ≡ 4 mod 8 → 2-way (free)
  constexpr int AG = CPAD/8;
  constexpr size_t ABYTES = (size_t)66*ASTR*2;
  constexpr size_t OBYTES = (size_t)64*OSTR*4;
  constexpr size_t LBYTES = (ABYTES > OBYTES) ? ABYTES : OBYTES;
  __shared__ __attribute__((aligned(16))) char LDS[LBYTES];
  short* A_s = (short*)LDS;
  float* OT  = (float*)LDS;            // aliases A_s; used after barrier
  int tid = threadIdx.x;
  int i0 = blockIdx.x*64;
  int wv = tid >> 6, lane = tid & 63;
  int lm = lane & 15, lk = lane >> 4;

  const short* wBw = wB + (size_t)wv*NSTEP2*1024 + (size_t)lane*8;
  auto LB = [&](int ss, int ni){
    return as_bf16x8(*(const short8*)(wBw + (ss*2 + ni)*512));
  };
  // issue first PF steps' B loads before the barrier (independent of LDS)
  bf16x8 bq[PF][2];
  #pragma unroll
  for (int s = 0; s < PF; ++s){ bq[s][0] = LB(s,0); bq[s][1] = LB(s,1); }

  // stage A once: rows i0-1 .. i0+64, cols [coff, coff+CPAD) clipped to cin
  for (int idx = tid; idx < 66*AG; idx += 256){
    int r = idx / AG, g = idx - r*AG;
    int pos = i0 - 1 + r;
    short8 v = {0,0,0,0,0,0,0,0};
    if (pos >= 0 && pos < n && g*8 < cin){
      const short* sp = src + (size_t)pos*sstride + coff + g*8;
      if (g*8 + 8 <= cin) v = *(const short8*)sp;
      else { for (int j = 0; g*8 + j < cin; ++j) v[j] = sp[j]; }
    }
    *(short8*)(A_s + r*ASTR + g*8) = v;
  }
  __syncthreads();

  f32x4 acc[4][2] = {};
  #pragma unroll
  for (int ss = 0; ss < NSTEP2; ++ss){
    int slot = ss % PF;                      // constant after unroll
    bf16x8 b0 = bq[slot][0], b1 = bq[slot][1];
    if (ss + PF < NSTEP2){ bq[slot][0] = LB(ss+PF,0); bq[slot][1] = LB(ss+PF,1); }
    int q = ss >> 1, ksub = ss & 1;
    int tp = q / KC, c = q - tp*KC;
    bf16x8 a[4];
    #pragma unroll
    for (int mi = 0; mi < 4; ++mi)
      a[mi] = as_bf16x8(*(const short8*)(A_s + (mi*16+lm+tp)*ASTR + c*64 + ksub*32 + lk*8));
    #pragma unroll
    for (int mi = 0; mi < 4; ++mi){
      acc[mi][0] = __builtin_amdgcn_mfma_f32_16x16x32_bf16(a[mi], b0, acc[mi][0], 0, 0, 0);
      acc[mi][1] = __builtin_amdgcn_mfma_f32_16x16x32_bf16(a[mi], b1, acc[mi][1], 0, 0, 0);
    }
  }
  __syncthreads();   // all A_s reads done before OT (alias) writes
  // epilogue: acc -> LDS f32 [64][OSTR] -> vector bf16 stores
  float b0s = bias[wv*32 + lm], b1s = bias[wv*32 + 16 + lm];
  #pragma unroll
  for (int mi = 0; mi < 4; ++mi)
    #pragma unroll
    for (int ni = 0; ni < 2; ++ni){
      float bb = ni ? b1s : b0s;
      #pragma unroll
      for (int r = 0; r < 4; ++r)
        OT[(mi*16 + lk*4 + r)*OSTR + wv*32 + ni*16 + lm] = fmaxf(acc[mi][ni][r] + bb, 0.f);
    }
  __syncthreads();
  {
    int r = tid >> 2, q = tid & 3;
    const float* row = OT + r*OSTR + q*32;
    short o[32];
    #pragma unroll
    for (int jc = 0; jc < 8; ++jc){
      f32x4 v = *(const f32x4*)(row + jc*4);
      #pragma unroll
      for (int e = 0; e < 4; ++e) o[jc*4+e] = f2bf(v[e]);
    }
    short* dp = dst + (size_t)(i0 + r)*dstride + q*32;
    #pragma unroll
    for (int v8 = 0; v8 < 4; ++v8) *(short8*)(dp + v8*8) = *(short8*)(o + v8*8);
  }
}

// ---------------- MFMA merge: (NMRG x 1088) x (1088 x 128); A LDS-dbuf, B reg-stream ----
__global__ __launch_bounds__(256) void k_mergem3(const short* __restrict__ Xf,
    const short* __restrict__ wB, const float* __restrict__ bias, short* __restrict__ dst)
{
  constexpr size_t OBYTES = (size_t)64*OSTR*4;   // 33792 > 16384 A-dbuf bytes
  __shared__ __attribute__((aligned(16))) char LDS[OBYTES];
  short* A_s = (short*)LDS;
  float* OT  = (float*)LDS;
  int tid = threadIdx.x;
  int j0 = blockIdx.x*64;
  int wv = tid >> 6, lane = tid & 63;
  int lm = lane & 15, lk = lane >> 4;
  auto stageA = [&](int s){
    #pragma unroll
    for (int it = 0; it < 2; ++it){
      int slot = it*256 + tid;               // 512 16B-units: [64 rows][8 chunks]
      int r = slot >> 3, kv = slot & 7;
      const short* gp = Xf + (size_t)(j0 + r)*1088 + s*64 + ((kv ^ (r&7))*8);
      gld16(gp, A_s + (s&1)*4096 + slot*8);
    }
  };
  const short* wBl = wB + (size_t)wv*17*2048 + (size_t)lane*8;
  auto LB = [&](int s, int ks, int ni){
    return as_bf16x8(*(const short8*)(wBl + ((size_t)(s*2 + ks)*2 + ni)*512));
  };
  bf16x8 c00 = LB(0,0,0), c01 = LB(0,0,1), c10 = LB(0,1,0), c11 = LB(0,1,1);
  stageA(0);
  __syncthreads();
  f32x4 acc[4][2] = {};
  for (int s = 0; s < 17; ++s){
    bf16x8 n00, n01, n10, n11;
    if (s < 16){
      n00 = LB(s+1,0,0); n01 = LB(s+1,0,1); n10 = LB(s+1,1,0); n11 = LB(s+1,1,1);
      stageA(s+1);
    }
    const short* Ab = A_s + (s&1)*4096;
    bf16x8 a[4];
    #pragma unroll
    for (int mi = 0; mi < 4; ++mi){
      int r = mi*16 + lm;
      a[mi] = as_bf16x8(*(const short8*)(Ab + r*64 + ((lk ^ (r&7))*8)));
    }
    #pragma unroll
    for (int mi = 0; mi < 4; ++mi){
      acc[mi][0] = __builtin_amdgcn_mfma_f32_16x16x32_bf16(a[mi], c00, acc[mi][0], 0, 0, 0);
      acc[mi][1] = __builtin_amdgcn_mfma_f32_16x16x32_bf16(a[mi], c01, acc[mi][1], 0, 0, 0);
    }
    #pragma unroll
    for (int mi = 0; mi < 4; ++mi){
      int r = mi*16 + lm;
      a[mi] = as_bf16x8(*(const short8*)(Ab + r*64 + (((4+lk) ^ (r&7))*8)));
    }
    #pragma unroll
    for (int mi = 0; mi < 4; ++mi){
      acc[mi][0] = __builtin_amdgcn_mfma_f32_16x16x32_bf16(a[mi], c10, acc[mi][0], 0, 0, 0);
      acc[mi][1] = __builtin_amdgcn_mfma_f32_16x16x32_bf16(a[mi], c11, acc[mi][1], 0, 0, 0);
    }
    __syncthreads();
    c00 = n00; c01 = n01; c10 = n10; c11 = n11;
  }
  float b0 = bias[wv*32 + lm], b1 = bias[wv*32 + 16 + lm];
  #pragma unroll
  for (int mi = 0; mi < 4; ++mi)
    #pragma unroll
    for (int ni = 0; ni < 2; ++ni){
      float bb = ni ? b1 : b0;
      #pragma unroll
      for (int r = 0; r < 4; ++r)
        OT[(mi*16 + lk*4 + r)*OSTR + wv*32 + ni*16 + lm] = fmaxf(acc[mi][ni][r] + bb, 0.f);
    }
  __syncthreads();
  {
    int r = tid >> 2, q = tid & 3;
    const float* row = OT + r*OSTR + q*32;
    short o[32];
    #pragma unroll
    for (int jc = 0; jc < 8; ++jc){
      f32x4 v = *(const f32x4*)(row + jc*4);
      #pragma unroll
      for (int e = 0; e < 4; ++e) o[jc*4+e] = f2bf(v[e]);
    }
    short* dp = dst + (size_t)(j0 + r)*128 + q*32;
    #pragma unroll
    for (int v8 = 0; v8 < 4; ++v8) *(short8*)(dp + v8*8) = *(short8*)(o + v8*8);
  }
}

// ---------------- flags head: sigmoid over reordered Wf2[272][4], vectorized ----------------
__global__ __launch_bounds__(256) void k_flags2(short* __restrict__ Xcat,
    const float* __restrict__ Wf2, const float* __restrict__ bf, float* __restrict__ F){
  size_t i = (size_t)blockIdx.x*256 + threadIdx.x;
  const short* x = Xcat + i*272;
  float a0 = bf[0], a1 = bf[1], a2 = bf[2], a3 = bf[3];
  for (int g = 0; g < 34; ++g){
    short8 x8 = *(const short8*)(x + g*8);
    #pragma unroll
    for (int e = 0; e < 8; ++e){
      float xv = bf2f(x8[e]);
      const float* w = Wf2 + (g*8+e)*4;
      a0 = fmaf(xv,w[0],a0); a1 = fmaf(xv,w[1],a1); a2 = fmaf(xv,w[2],a2); a3 = fmaf(xv,w[3],a3);
    }
  }
  float f0 = 1.f/(1.f+expf(-a0)), f1 = 1.f/(1.f+expf(-a1));
  float f2 = 1.f/(1.f+expf(-a2)), f3 = 1.f/(1.f+expf(-a3));
  float* f = F + i*4;
  f[0]=f0; f[1]=f1; f[2]=f2; f[3]=f3;
  short* xc = Xcat + i*272 + 128;
  xc[0]=f2bf(f0); xc[1]=f2bf(f1); xc[2]=f2bf(f2); xc[3]=f2bf(f3);
}

// ---------------- output head ----------------
__global__ __launch_bounds__(256) void k_out(const short* __restrict__ S,
    const float* __restrict__ F, const float* __restrict__ Ws, const float* __restrict__ bs,
    float* __restrict__ out, int b){
  size_t j = (size_t)blockIdx.x*256 + threadIdx.x;
  float l[16];
  #pragma unroll
  for (int t = 0; t < 16; ++t) l[t] = bs[t];
  const short* s = S + j*128;
  for (int g = 0; g < 16; ++g){
    short8 x8 = *(const short8*)(s + g*8);
    #pragma unroll
    for (int e = 0; e < 8; ++e){
      float x = bf2f(x8[e]);
      const float* w = Ws + (g*8+e)*16;
      #pragma unroll
      for (int t = 0; t < 16; ++t) l[t] = fmaf(x, w[t], l[t]);
    }
  }
  float m = l[0];
  #pragma unroll
  for (int t = 1; t < 16; ++t) m = fmaxf(m, l[t]);
  float sum = 0.f;
  #pragma unroll
  for (int t = 0; t < 16; ++t){ l[t] = expf(l[t]-m); sum += l[t]; }
  float inv = 1.f/sum;
  float* o = out + ((size_t)b*NMRG + j)*20;
  #pragma unroll
  for (int k = 0; k < 4; ++k){
    size_t r = (size_t)(4*j + k)*4;
    o[k] = F[r] - F[r+1];
  }
  #pragma unroll
  for (int t = 0; t < 16; ++t) o[4+t] = l[t]*inv;
}

extern "C" void kernel_launch(void* const* d_in, const int* in_sizes, int n_in,
                              void* d_out, int out_size, void* d_ws, size_t ws_size,
                              hipStream_t stream){
  const float* inp     = (const float*)d_in[0];
  const float* w_pre0  = (const float*)d_in[1];
  const float* b_pre0  = (const float*)d_in[2];
  const float* w_pre1  = (const float*)d_in[3];
  const float* b_pre1  = (const float*)d_in[4];
  const float* w_flags = (const float*)d_in[5];
  const float* b_flags = (const float*)d_in[6];
  const float* w_merge = (const float*)d_in[7];
  const float* b_merge = (const float*)d_in[8];
  const float* w_post[4] = {(const float*)d_in[9], (const float*)d_in[11],
                            (const float*)d_in[13], (const float*)d_in[15]};
  const float* b_post[4] = {(const float*)d_in[10], (const float*)d_in[12],
                            (const float*)d_in[14], (const float*)d_in[16]};
  const float* w_sym   = (const float*)d_in[17];
  const float* b_sym   = (const float*)d_in[18];
  float* outp = (float*)d_out;

  char* p = (char*)d_ws;
  unsigned* kA = (unsigned*)p; p += (size_t)NSORT*NPOS*4;
  unsigned* vA = (unsigned*)p; p += (size_t)NSORT*NPOS*4;
  unsigned* kB = (unsigned*)p; p += (size_t)NSORT*NPOS*4;
  unsigned* vB = (unsigned*)p; p += (size_t)NSORT*NPOS*4;
  unsigned* hist = (unsigned*)p; p += (size_t)NSORT*65536*4;
  short* XA   = (short*)p; p += (size_t)NPOS*224*2;
  short* Xcat = (short*)p; p += (size_t)NPOS*272*2;
  float* Fbuf = (float*)p; p += (size_t)NPOS*4*4;
  short* M0   = (short*)p; p += (size_t)NMRG*128*2;
  short* M1   = (short*)p; p += (size_t)NMRG*128*2;
  short* wb0  = (short*)p; p += (size_t)3*2*8192*2;
  short* wb1  = (short*)p; p += (size_t)3*4*8192*2;
  short* wbq0 = (short*)p; p += (size_t)3*2*8192*2;
  short* wbq1 = (short*)p; p += (size_t)3*2*8192*2;
  short* wbq2 = (short*)p; p += (size_t)3*2*8192*2;
  short* wbq3 = (short*)p; p += (size_t)3*2*8192*2;
  short* wbm  = (short*)p; p += (size_t)17*8192*2;
  float* wf2  = (float*)p; p += (size_t)272*4*4;
  if ((size_t)(p - (char*)d_ws) > ws_size) return;
  short* wbq[4] = {wbq0, wbq1, wbq2, wbq3};

  // weight prep (cheap, once per call); lane-major layouts
  k_prepB<<<(6144 +255)/256, 256, 0, stream>>>(w_pre0, wb0, 2, 6, 0, 6144);
  k_prepB<<<(12288+255)/256, 256, 0, stream>>>(w_pre1, wb1, 4, 12, 1, 12288);
  for (int i = 0; i < 4; ++i)
    k_prepB<<<(6144+255)/256, 256, 0, stream>>>(w_post[i], wbq[i], 2, 6, 2, 6144);
  k_prepB<<<(17408+255)/256, 256, 0, stream>>>(w_merge, wbm, 17, 17, 3, 17408);
  k_prepWf<<<5, 256, 0, stream>>>(w_flags, wf2);

  // sorts
  k_make_keys<<<NSORT*NPOS/256, 256, 0, stream>>>(inp, kA, vA);
  unsigned *sk = kA, *sv = vA, *dk = kB, *dv = vB;
  for (int pass = 0; pass < 4; ++pass){
    int shift = pass*8;
    k_hist<<<NSORT*TPS, 256, 0, stream>>>(sk, hist, shift);
    k_scan<<<NSORT, 256, 0, stream>>>(hist);
    k_scatter<<<NSORT*TPS, 64, 0, stream>>>(sk, sv, dk, dv, hist, shift);
    unsigned* t;
    t = sk; sk = dk; dk = t;
    t = sv; sv = dv; dv = t;
  }
  for (int b = 0; b < 2; ++b){
    const unsigned* P0 = sv + (size_t)(b*2+0)*NPOS;  // argsort of ch 3
    const unsigned* P1 = sv + (size_t)(b*2+1)*NPOS;  // argsort of ch 4
    k_gath<<<NPOS*128/256, 256, 0, stream>>>(inp, P1, P0, XA, Xcat, b);
    k_conv3p<128><<<NPOS/64, 256, 0, stream>>>(XA, 224, 128, 69,  wb0, b_pre0, XA,   224, NPOS);
    k_conv3p<256><<<NPOS/64, 256, 0, stream>>>(XA, 224, 0,   197, wb1, b_pre1, Xcat, 272, NPOS);
    k_flags2<<<NPOS/256, 256, 0, stream>>>(Xcat, wf2, b_flags, Fbuf);
    k_mergem3<<<NMRG/64, 256, 0, stream>>>(Xcat, wbm, b_merge, M0);
    k_conv3p<128><<<NMRG/64, 256, 0, stream>>>(M0, 128, 0, 128, wbq[0], b_post[0], M1, 128, NMRG);
    k_conv3p<128><<<NMRG/64, 256, 0, stream>>>(M1, 128, 0, 128, wbq[1], b_post[1], M0, 128, NMRG);
    k_conv3p<128><<<NMRG/64, 256, 0, stream>>>(M0, 128, 0, 128, wbq[2], b_post[2], M1, 128, NMRG);
    k_conv3p<128><<<NMRG/64, 256, 0, stream>>>(M1, 128, 0, 128, wbq[3], b_post[3], M0, 128, NMRG);
    k_out<<<NMRG/256, 256, 0, stream>>>(M0, Fbuf, w_sym, b_sym, outp, b);
  }
}

// Round 10
// 598.813 us; speedup vs baseline: 1.0693x; 1.0693x over previous
//
#include <hip/hip_runtime.h>
#include <hip/hip_bf16.h>
#include <math.h>

#define NPOS 131072   // N
#define NF   69       // FEAT
#define NMRG 32768    // N/4
#define TILE 2048
#define TPS  64       // NPOS/TILE
#define NSORT 4
#define EPT  16
#define XCW  288      // Xcat row width (bf16): [conv1 0..127][F 128..131][x0 132..200][0 201..207][g 208..276][0 277..287]

typedef __attribute__((ext_vector_type(8))) short short8;
typedef __attribute__((ext_vector_type(4))) short s16x4;
typedef __bf16 bf16x8 __attribute__((ext_vector_type(8)));
typedef __attribute__((ext_vector_type(4))) float f32x4;

static __device__ inline bf16x8 as_bf16x8(short8 v){ union{short8 s; bf16x8 b;} u; u.s=v; return u.b; }
static __device__ inline short f2bf(float x){ __hip_bfloat16 h = __float2bfloat16(x); return *(short*)&h; }
static __device__ inline float bf2f(short s){ return __uint_as_float(((unsigned)(unsigned short)s)<<16); }

// async global->LDS, 16B per lane; LDS dest = wave-uniform base + lane*16 (linear)
static __device__ inline void gld16(const short* g, short* l){
  __builtin_amdgcn_global_load_lds(
      (const __attribute__((address_space(1))) unsigned int*)g,
      (__attribute__((address_space(3))) unsigned int*)l, 16, 0, 0);
}

// ---------------- stable argsort: LSD radix, 4x8-bit (R7 version) ----------------
__global__ void k_make_keys(const float* __restrict__ inp, unsigned* __restrict__ kA,
                            unsigned* __restrict__ vA){
  unsigned t = blockIdx.x*256u + threadIdx.x;
  unsigned s = t >> 17, i = t & (NPOS-1u);
  unsigned b = s >> 1, ch = 3u + (s & 1u);
  float x = inp[((size_t)b*NPOS + i)*NF + ch];
  unsigned u = __float_as_uint(x);
  u = (u & 0x80000000u) ? ~u : (u | 0x80000000u);
  kA[t] = u; vA[t] = i;
}

__global__ __launch_bounds__(256) void k_hist(const unsigned* __restrict__ src,
                                              unsigned* __restrict__ hist, int shift){
  __shared__ unsigned h[256];
  int tid = threadIdx.x;
  h[tid] = 0u; __syncthreads();
  int s = blockIdx.x / TPS, tile = blockIdx.x % TPS;
  const unsigned* ks = src + (size_t)s*NPOS + (size_t)tile*TILE;
  for (int r = 0; r < TILE/256; ++r){
    unsigned d = (ks[r*256 + tid] >> shift) & 255u;
    atomicAdd(&h[d], 1u);
  }
  __syncthreads();
  hist[s*16384 + tid*TPS + tile] = h[tid];
}

__global__ __launch_bounds__(256) void k_scan(unsigned* __restrict__ hist){
  __shared__ unsigned tot[256];
  int tid = threadIdx.x; int s = blockIdx.x;
  unsigned* g = hist + s*16384;
  unsigned sum = 0;
  for (int q = 0; q < TPS; ++q) sum += g[tid*TPS + q];
  tot[tid] = sum;
  __syncthreads();
  if (tid == 0){
    unsigned run = 0;
    for (int t = 0; t < 256; ++t){ unsigned tmp = tot[t]; tot[t] = run; run += tmp; }
  }
  __syncthreads();
  unsigned run = tot[tid];
  for (int q = 0; q < TPS; ++q){ unsigned tmp = g[tid*TPS+q]; g[tid*TPS+q] = run; run += tmp; }
}

__global__ __launch_bounds__(128) void k_scatter(const unsigned* __restrict__ srcK,
    const unsigned* __restrict__ srcV, unsigned* __restrict__ dstK, unsigned* __restrict__ dstV,
    const unsigned* __restrict__ off, int shift){
  __shared__ unsigned short cnt[256*128];
  int tid = threadIdx.x;
  unsigned* cz = (unsigned*)cnt;
  for (int idx = tid; idx < 256*128/2; idx += 128) cz[idx] = 0u;
  __syncthreads();
  int s = blockIdx.x / TPS, tile = blockIdx.x % TPS;
  const unsigned* ks = srcK + (size_t)s*NPOS + (size_t)tile*TILE;
  const unsigned* vs = srcV + (size_t)s*NPOS + (size_t)tile*TILE;
  unsigned k8[EPT], v8[EPT];
  #pragma unroll
  for (int r = 0; r < EPT; ++r){
    k8[r] = ks[tid*EPT + r];
    v8[r] = vs[tid*EPT + r];
    unsigned d = (k8[r] >> shift) & 255u;
    cnt[d*128 + tid]++;
  }
  __syncthreads();
  for (int dd = 0; dd < 2; ++dd){
    int d = tid + dd*128;
    unsigned run = 0;
    for (int t = 0; t < 128; ++t){ unsigned tmp = cnt[d*128 + t]; cnt[d*128 + t] = (unsigned short)run; run += tmp; }
  }
  __syncthreads();
  const unsigned* ob = off + s*16384;
  #pragma unroll
  for (int r = 0; r < EPT; ++r){
    unsigned d = (k8[r] >> shift) & 255u;
    unsigned rk = cnt[d*128 + tid];
    cnt[d*128 + tid] = (unsigned short)(rk + 1u);
    unsigned pos = ob[d*TPS + tile] + rk;
    dstK[(size_t)s*NPOS + pos] = k8[r];
    dstV[(size_t)s*NPOS + pos] = v8[r];
  }
}

// ---------------- bf16 pre-convert: inp row (69 f32) -> inpb row (72 bf16, 16B-aligned) ----
__global__ __launch_bounds__(256) void k_cvt(const float* __restrict__ inp,
                                             short* __restrict__ inpb, int b){
  int t = blockIdx.x*256 + threadIdx.x;   // NPOS*9
  int i = t/9, q = t - i*9;
  const float* sp = inp + ((size_t)b*NPOS + i)*NF + q*8;
  short o[8];
  #pragma unroll
  for (int e = 0; e < 8; ++e){
    int c = q*8 + e;
    o[e] = (c < NF) ? f2bf(sp[e]) : (short)0;
  }
  *(short8*)(inpb + (size_t)i*72 + q*8) = *(short8*)o;
}

// ---------------- gather from L2-resident bf16 rows ----------------
// XA  [224]: [conv0out 0..127][x0 128..196][pad]
// Xcat[288]: layout per XCW comment above
__global__ __launch_bounds__(256) void k_gath2(const short* __restrict__ inpb,
    const unsigned* __restrict__ P1, const unsigned* __restrict__ P0,
    short* __restrict__ XA, short* __restrict__ Xcat){
  int t = blockIdx.x*256 + threadIdx.x;   // NPOS*18
  int i = t/18, u = t - i*18;
  int p = u/9, q = u - p*9;
  if (p){  // x0 rows (sorted by ch4)
    short8 v = *(const short8*)(inpb + (size_t)P1[i]*72 + q*8);
    *(short8*)(XA + (size_t)i*224 + 128 + q*8) = v;
    s16x4 lo = {v[0],v[1],v[2],v[3]}, hi = {v[4],v[5],v[6],v[7]};
    *(s16x4*)(Xcat + (size_t)i*XCW + 132 + q*8) = lo;
    *(s16x4*)(Xcat + (size_t)i*XCW + 136 + q*8) = hi;
  } else {  // g rows (sorted by ch3)
    short8 v = *(const short8*)(inpb + (size_t)P0[i]*72 + q*8);
    *(short8*)(Xcat + (size_t)i*XCW + 208 + q*8) = v;
    if (q == 8){
      s16x4 z4 = {0,0,0,0};
      *(s16x4*)(Xcat + (size_t)i*XCW + 204) = z4;
      short8 z8 = {0,0,0,0,0,0,0,0};
      *(short8*)(Xcat + (size_t)i*XCW + 280) = z8;
    }
  }
}

// ---------------- weight prep: lane-major [wv][q][ksub][ni][lane][8] ----------------
__global__ void k_prepB(const float* __restrict__ w, short* __restrict__ out,
                        int KC, int NQ, int mode, int total){
  int t = blockIdx.x*256 + threadIdx.x;   // one 16B unit (8 weights) per thread
  if (t >= total) return;
  int lane = t & 63, ni = (t>>6) & 1, ksub = (t>>7) & 1;
  int rest = t >> 8;
  int q = rest % NQ;
  int wv = rest / NQ;
  int tap = q / KC, cc = q - tap*KC;
  int nn = wv*32 + ni*16 + (lane & 15);
  int chb = cc*64 + ksub*32 + ((lane >> 4) & 3)*8;
  short o[8];
  #pragma unroll
  for (int e = 0; e < 8; ++e){
    int ch = chb + e;
    float val = 0.f;
    if (mode == 0){ if (ch < 69)  val = w[((size_t)tap*69  + ch)*128 + nn]; }
    else if (mode == 1){
      if (ch < 128)      val = w[((size_t)tap*197 + 69 + ch)*128 + nn];
      else if (ch < 197) val = w[((size_t)tap*197 + ch - 128)*128 + nn];
    }
    else if (mode == 2){ if (ch < 128) val = w[((size_t)tap*128 + ch)*128 + nn]; }
    else {
      int tm = ch / XCW, cm = ch - tm*XCW;
      int orig = -1;
      if (cm < 128)                     orig = 73 + cm;      // conv1out
      else if (cm < 201)                orig = cm - 128;      // F(0..3) + x0(4..72)
      else if (cm >= 208 && cm < 277)   orig = cm - 7;        // g: 201..269
      if (orig >= 0) val = w[((size_t)tm*270 + orig)*128 + nn];
    }
    o[e] = f2bf(val);
  }
  *(short8*)(out + (size_t)t*8) = *(short8*)o;
}

__global__ void k_prepWf(const float* __restrict__ wf, float* __restrict__ out){
  int t = blockIdx.x*256 + threadIdx.x;   // XCW*4
  if (t >= XCW*4) return;
  int c = t >> 2, q = t & 3;
  float v = 0.f;
  if (c < 128)                  v = wf[(69 + c)*4 + q];
  else if (c >= 132 && c < 201) v = wf[(c - 132)*4 + q];
  else if (c >= 208 && c < 277) v = wf[(197 + c - 208)*4 + q];
  out[t] = v;
}

#define OSTR 132   // f32 epilogue stride: 132 dwords = 528B, 16B-aligned, banks spread

// ---------------- MFMA conv3: 4-deep B-prefetch ring, barrier-free K-loop ----------------
template<int CPAD>
__global__ __launch_bounds__(256) void k_conv3p(
    const short* __restrict__ src, int sstride, int coff, int cin,
    const short* __restrict__ wB, const float* __restrict__ bias,
    short* __restrict__ dst, int dstride, int n)
{
  constexpr int KC = CPAD/64;
  constexpr int NSTEP2 = 3*KC*2;
  constexpr int PF = 4;
  constexpr int ASTR = CPAD + 8;
  constexpr int AG = CPAD/8;
  constexpr size_t ABYTES = (size_t)66*ASTR*2;
  constexpr size_t OBYTES = (size_t)64*OSTR*4;
  constexpr size_t LBYTES = (ABYTES > OBYTES) ? ABYTES : OBYTES;
  __shared__ __attribute__((aligned(16))) char LDS[LBYTES];
  short* A_s = (short*)LDS;
  float* OT  = (float*)LDS;
  int tid = threadIdx.x;
  int i0 = blockIdx.x*64;
  int wv = tid >> 6, lane = tid & 63;
  int lm = lane & 15, lk = lane >> 4;

  const short* wBw = wB + (size_t)wv*NSTEP2*1024 + (size_t)lane*8;
  auto LB = [&](int ss, int ni){
    return as_bf16x8(*(const short8*)(wBw + (ss*2 + ni)*512));
  };
  bf16x8 bq[PF][2];
  #pragma unroll
  for (int s = 0; s < PF; ++s){ bq[s][0] = LB(s,0); bq[s][1] = LB(s,1); }

  for (int idx = tid; idx < 66*AG; idx += 256){
    int r = idx / AG, g = idx - r*AG;
    int pos = i0 - 1 + r;
    short8 v = {0,0,0,0,0,0,0,0};
    if (pos >= 0 && pos < n && g*8 < cin){
      const short* sp = src + (size_t)pos*sstride + coff + g*8;
      if (g*8 + 8 <= cin) v = *(const short8*)sp;
      else { for (int j = 0; g*8 + j < cin; ++j) v[j] = sp[j]; }
    }
    *(short8*)(A_s + r*ASTR + g*8) = v;
  }
  __syncthreads();

  f32x4 acc[4][2] = {};
  #pragma unroll
  for (int ss = 0; ss < NSTEP2; ++ss){
    int slot = ss % PF;
    bf16x8 b0 = bq[slot][0], b1 = bq[slot][1];
    if (ss + PF < NSTEP2){ bq[slot][0] = LB(ss+PF,0); bq[slot][1] = LB(ss+PF,1); }
    int q = ss >> 1, ksub = ss & 1;
    int tp = q / KC, c = q - tp*KC;
    bf16x8 a[4];
    #pragma unroll
    for (int mi = 0; mi < 4; ++mi)
      a[mi] = as_bf16x8(*(const short8*)(A_s + (mi*16+lm+tp)*ASTR + c*64 + ksub*32 + lk*8));
    #pragma unroll
    for (int mi = 0; mi < 4; ++mi){
      acc[mi][0] = __builtin_amdgcn_mfma_f32_16x16x32_bf16(a[mi], b0, acc[mi][0], 0, 0, 0);
      acc[mi][1] = __builtin_amdgcn_mfma_f32_16x16x32_bf16(a[mi], b1, acc[mi][1], 0, 0, 0);
    }
  }
  __syncthreads();
  float b0s = bias[wv*32 + lm], b1s = bias[wv*32 + 16 + lm];
  #pragma unroll
  for (int mi = 0; mi < 4; ++mi)
    #pragma unroll
    for (int ni = 0; ni < 2; ++ni){
      float bb = ni ? b1s : b0s;
      #pragma unroll
      for (int r = 0; r < 4; ++r)
        OT[(mi*16 + lk*4 + r)*OSTR + wv*32 + ni*16 + lm] = fmaxf(acc[mi][ni][r] + bb, 0.f);
    }
  __syncthreads();
  {
    int r = tid >> 2, q = tid & 3;
    const float* row = OT + r*OSTR + q*32;
    short o[32];
    #pragma unroll
    for (int jc = 0; jc < 8; ++jc){
      f32x4 v = *(const f32x4*)(row + jc*4);
      #pragma unroll
      for (int e = 0; e < 4; ++e) o[jc*4+e] = f2bf(v[e]);
    }
    short* dp = dst + (size_t)(i0 + r)*dstride + q*32;
    #pragma unroll
    for (int v8 = 0; v8 < 4; ++v8) *(short8*)(dp + v8*8) = *(short8*)(o + v8*8);
  }
}

// ---------------- MFMA merge: (NMRG x 1152) x (1152 x 128); A LDS-dbuf, B reg-stream ----
__global__ __launch_bounds__(256) void k_mergem3(const short* __restrict__ Xf,
    const short* __restrict__ wB, const float* __restrict__ bias, short* __restrict__ dst)
{
  constexpr int NS = 4*XCW/64;                   // 18
  constexpr size_t OBYTES = (size_t)64*OSTR*4;   // 33792 > 16384 A-dbuf bytes
  __shared__ __attribute__((aligned(16))) char LDS[OBYTES];
  short* A_s = (short*)LDS;
  float* OT  = (float*)LDS;
  int tid = threadIdx.x;
  int j0 = blockIdx.x*64;
  int wv = tid >> 6, lane = tid & 63;
  int lm = lane & 15, lk = lane >> 4;
  auto stageA = [&](int s){
    #pragma unroll
    for (int it = 0; it < 2; ++it){
      int slot = it*256 + tid;               // 512 16B-units: [64 rows][8 chunks]
      int r = slot >> 3, kv = slot & 7;
      const short* gp = Xf + (size_t)(j0 + r)*(4*XCW) + s*64 + ((kv ^ (r&7))*8);
      gld16(gp, A_s + (s&1)*4096 + slot*8);
    }
  };
  const short* wBl = wB + (size_t)wv*NS*2048 + (size_t)lane*8;
  auto LB = [&](int s, int ks, int ni){
    return as_bf16x8(*(const short8*)(wBl + ((size_t)(s*2 + ks)*2 + ni)*512));
  };
  bf16x8 c00 = LB(0,0,0), c01 = LB(0,0,1), c10 = LB(0,1,0), c11 = LB(0,1,1);
  stageA(0);
  __syncthreads();
  f32x4 acc[4][2] = {};
  for (int s = 0; s < NS; ++s){
    bf16x8 n00, n01, n10, n11;
    if (s < NS-1){
      n00 = LB(s+1,0,0); n01 = LB(s+1,0,1); n10 = LB(s+1,1,0); n11 = LB(s+1,1,1);
      stageA(s+1);
    }
    const short* Ab = A_s + (s&1)*4096;
    bf16x8 a[4];
    #pragma unroll
    for (int mi = 0; mi < 4; ++mi){
      int r = mi*16 + lm;
      a[mi] = as_bf16x8(*(const short8*)(Ab + r*64 + ((lk ^ (r&7))*8)));
    }
    #pragma unroll
    for (int mi = 0; mi < 4; ++mi){
      acc[mi][0] = __builtin_amdgcn_mfma_f32_16x16x32_bf16(a[mi], c00, acc[mi][0], 0, 0, 0);
      acc[mi][1] = __builtin_amdgcn_mfma_f32_16x16x32_bf16(a[mi], c01, acc[mi][1], 0, 0, 0);
    }
    #pragma unroll
    for (int mi = 0; mi < 4; ++mi){
      int r = mi*16 + lm;
      a[mi] = as_bf16x8(*(const short8*)(Ab + r*64 + (((4+lk) ^ (r&7))*8)));
    }
    #pragma unroll
    for (int mi = 0; mi < 4; ++mi){
      acc[mi][0] = __builtin_amdgcn_mfma_f32_16x16x32_bf16(a[mi], c10, acc[mi][0], 0, 0, 0);
      acc[mi][1] = __builtin_amdgcn_mfma_f32_16x16x32_bf16(a[mi], c11, acc[mi][1], 0, 0, 0);
    }
    __syncthreads();
    c00 = n00; c01 = n01; c10 = n10; c11 = n11;
  }
  float b0 = bias[wv*32 + lm], b1 = bias[wv*32 + 16 + lm];
  #pragma unroll
  for (int mi = 0; mi < 4; ++mi)
    #pragma unroll
    for (int ni = 0; ni < 2; ++ni){
      float bb = ni ? b1 : b0;
      #pragma unroll
      for (int r = 0; r < 4; ++r)
        OT[(mi*16 + lk*4 + r)*OSTR + wv*32 + ni*16 + lm] = fmaxf(acc[mi][ni][r] + bb, 0.f);
    }
  __syncthreads();
  {
    int r = tid >> 2, q = tid & 3;
    const float* row = OT + r*OSTR + q*32;
    short o[32];
    #pragma unroll
    for (int jc = 0; jc < 8; ++jc){
      f32x4 v = *(const f32x4*)(row + jc*4);
      #pragma unroll
      for (int e = 0; e < 4; ++e) o[jc*4+e] = f2bf(v[e]);
    }
    short* dp = dst + (size_t)(j0 + r)*128 + q*32;
    #pragma unroll
    for (int v8 = 0; v8 < 4; ++v8) *(short8*)(dp + v8*8) = *(short8*)(o + v8*8);
  }
}

// ---------------- flags head ----------------
__global__ __launch_bounds__(256) void k_flags2(short* __restrict__ Xcat,
    const float* __restrict__ Wf2, const float* __restrict__ bf, float* __restrict__ F){
  size_t i = (size_t)blockIdx.x*256 + threadIdx.x;
  const short* x = Xcat + i*XCW;
  float a0 = bf[0], a1 = bf[1], a2 = bf[2], a3 = bf[3];
  for (int g = 0; g < XCW/8; ++g){
    short8 x8 = *(const short8*)(x + g*8);
    #pragma unroll
    for (int e = 0; e < 8; ++e){
      float xv = bf2f(x8[e]);
      const float* w = Wf2 + (g*8+e)*4;
      a0 = fmaf(xv,w[0],a0); a1 = fmaf(xv,w[1],a1); a2 = fmaf(xv,w[2],a2); a3 = fmaf(xv,w[3],a3);
    }
  }
  float f0 = 1.f/(1.f+expf(-a0)), f1 = 1.f/(1.f+expf(-a1));
  float f2 = 1.f/(1.f+expf(-a2)), f3 = 1.f/(1.f+expf(-a3));
  float* f = F + i*4;
  f[0]=f0; f[1]=f1; f[2]=f2; f[3]=f3;
  short* xc = Xcat + i*XCW + 128;
  xc[0]=f2bf(f0); xc[1]=f2bf(f1); xc[2]=f2bf(f2); xc[3]=f2bf(f3);
}

// ---------------- output head ----------------
__global__ __launch_bounds__(256) void k_out(const short* __restrict__ S,
    const float* __restrict__ F, const float* __restrict__ Ws, const float* __restrict__ bs,
    float* __restrict__ out, int b){
  size_t j = (size_t)blockIdx.x*256 + threadIdx.x;
  float l[16];
  #pragma unroll
  for (int t = 0; t < 16; ++t) l[t] = bs[t];
  const short* s = S + j*128;
  for (int g = 0; g < 16; ++g){
    short8 x8 = *(const short8*)(s + g*8);
    #pragma unroll
    for (int e = 0; e < 8; ++e){
      float x = bf2f(x8[e]);
      const float* w = Ws + (g*8+e)*16;
      #pragma unroll
      for (int t = 0; t < 16; ++t) l[t] = fmaf(x, w[t], l[t]);
    }
  }
  float m = l[0];
  #pragma unroll
  for (int t = 1; t < 16; ++t) m = fmaxf(m, l[t]);
  float sum = 0.f;
  #pragma unroll
  for (int t = 0; t < 16; ++t){ l[t] = expf(l[t]-m); sum += l[t]; }
  float inv = 1.f/sum;
  float* o = out + ((size_t)b*NMRG + j)*20;
  #pragma unroll
  for (int k = 0; k < 4; ++k){
    size_t r = (size_t)(4*j + k)*4;
    o[k] = F[r] - F[r+1];
  }
  #pragma unroll
  for (int t = 0; t < 16; ++t) o[4+t] = l[t]*inv;
}

extern "C" void kernel_launch(void* const* d_in, const int* in_sizes, int n_in,
                              void* d_out, int out_size, void* d_ws, size_t ws_size,
                              hipStream_t stream){
  const float* inp     = (const float*)d_in[0];
  const float* w_pre0  = (const float*)d_in[1];
  const float* b_pre0  = (const float*)d_in[2];
  const float* w_pre1  = (const float*)d_in[3];
  const float* b_pre1  = (const float*)d_in[4];
  const float* w_flags = (const float*)d_in[5];
  const float* b_flags = (const float*)d_in[6];
  const float* w_merge = (const float*)d_in[7];
  const float* b_merge = (const float*)d_in[8];
  const float* w_post[4] = {(const float*)d_in[9], (const float*)d_in[11],
                            (const float*)d_in[13], (const float*)d_in[15]};
  const float* b_post[4] = {(const float*)d_in[10], (const float*)d_in[12],
                            (const float*)d_in[14], (const float*)d_in[16]};
  const float* w_sym   = (const float*)d_in[17];
  const float* b_sym   = (const float*)d_in[18];
  float* outp = (float*)d_out;

  char* p = (char*)d_ws;
  unsigned* kA = (unsigned*)p; p += (size_t)NSORT*NPOS*4;
  unsigned* vA = (unsigned*)p; p += (size_t)NSORT*NPOS*4;
  unsigned* kB = (unsigned*)p; p += (size_t)NSORT*NPOS*4;
  unsigned* vB = (unsigned*)p; p += (size_t)NSORT*NPOS*4;
  unsigned* hist = (unsigned*)p; p += (size_t)NSORT*16384*4;
  short* inpb = (short*)p; p += (size_t)NPOS*72*2;
  short* XA   = (short*)p; p += (size_t)NPOS*224*2;
  short* Xcat = (short*)p; p += (size_t)NPOS*XCW*2;
  float* Fbuf = (float*)p; p += (size_t)NPOS*4*4;
  short* M0   = (short*)p; p += (size_t)NMRG*128*2;
  short* M1   = (short*)p; p += (size_t)NMRG*128*2;
  short* wb0  = (short*)p; p += (size_t)3*2*8192*2;
  short* wb1  = (short*)p; p += (size_t)3*4*8192*2;
  short* wbq0 = (short*)p; p += (size_t)3*2*8192*2;
  short* wbq1 = (short*)p; p += (size_t)3*2*8192*2;
  short* wbq2 = (short*)p; p += (size_t)3*2*8192*2;
  short* wbq3 = (short*)p; p += (size_t)3*2*8192*2;
  short* wbm  = (short*)p; p += (size_t)18*8192*2;   // 4wv*18q*2048 = 147456 shorts
  float* wf2  = (float*)p; p += (size_t)XCW*4*4;
  if ((size_t)(p - (char*)d_ws) > ws_size) return;
  short* wbq[4] = {wbq0, wbq1, wbq2, wbq3};

  // weight prep (cheap, once per call); lane-major layouts
  k_prepB<<<(6144 +255)/256, 256, 0, stream>>>(w_pre0, wb0, 2, 6, 0, 6144);
  k_prepB<<<(12288+255)/256, 256, 0, stream>>>(w_pre1, wb1, 4, 12, 1, 12288);
  for (int i = 0; i < 4; ++i)
    k_prepB<<<(6144+255)/256, 256, 0, stream>>>(w_post[i], wbq[i], 2, 6, 2, 6144);
  k_prepB<<<(18432+255)/256, 256, 0, stream>>>(w_merge, wbm, 18, 18, 3, 18432);
  k_prepWf<<<(XCW*4+255)/256, 256, 0, stream>>>(w_flags, wf2);

  // sorts
  k_make_keys<<<NSORT*NPOS/256, 256, 0, stream>>>(inp, kA, vA);
  unsigned *sk = kA, *sv = vA, *dk = kB, *dv = vB;
  for (int pass = 0; pass < 4; ++pass){
    int shift = pass*8;
    k_hist<<<NSORT*TPS, 256, 0, stream>>>(sk, hist, shift);
    k_scan<<<NSORT, 256, 0, stream>>>(hist);
    k_scatter<<<NSORT*TPS, 128, 0, stream>>>(sk, sv, dk, dv, hist, shift);
    unsigned* t;
    t = sk; sk = dk; dk = t;
    t = sv; sv = dv; dv = t;
  }
  for (int b = 0; b < 2; ++b){
    const unsigned* P0 = sv + (size_t)(b*2+0)*NPOS;  // argsort of ch 3
    const unsigned* P1 = sv + (size_t)(b*2+1)*NPOS;  // argsort of ch 4
    k_cvt<<<NPOS*9/256, 256, 0, stream>>>(inp, inpb, b);
    k_gath2<<<NPOS*18/256, 256, 0, stream>>>(inpb, P1, P0, XA, Xcat);
    k_conv3p<128><<<NPOS/64, 256, 0, stream>>>(XA, 224, 128, 69,  wb0, b_pre0, XA,   224, NPOS);
    k_conv3p<256><<<NPOS/64, 256, 0, stream>>>(XA, 224, 0,   197, wb1, b_pre1, Xcat, XCW, NPOS);
    k_flags2<<<NPOS/256, 256, 0, stream>>>(Xcat, wf2, b_flags, Fbuf);
    k_mergem3<<<NMRG/64, 256, 0, stream>>>(Xcat, wbm, b_merge, M0);
    k_conv3p<128><<<NMRG/64, 256, 0, stream>>>(M0, 128, 0, 128, wbq[0], b_post[0], M1, 128, NMRG);
    k_conv3p<128><<<NMRG/64, 256, 0, stream>>>(M1, 128, 0, 128, wbq[1], b_post[1], M0, 128, NMRG);
    k_conv3p<128><<<NMRG/64, 256, 0, stream>>>(M0, 128, 0, 128, wbq[2], b_post[2], M1, 128, NMRG);
    k_conv3p<128><<<NMRG/64, 256, 0, stream>>>(M1, 128, 0, 128, wbq[3], b_post[3], M0, 128, NMRG);
    k_out<<<NMRG/256, 256, 0, stream>>>(M0, Fbuf, w_sym, b_sym, outp, b);
  }
}

// Round 11
// 590.660 us; speedup vs baseline: 1.0840x; 1.0138x over previous
//
#include <hip/hip_runtime.h>
#include <hip/hip_bf16.h>
#include <math.h>

#define NPOS 131072   // N
#define NF   69       // FEAT
#define NMRG 32768    // N/4
#define TILE 2048
#define TPS  64       // NPOS/TILE
#define NSORT 4
#define EPT  16
#define XCW  288      // Xcat row width (bf16): [conv1 0..127][F 128..131][x0 132..200][0 201..207][g 208..276][0 277..287]

typedef __attribute__((ext_vector_type(8))) short short8;
typedef __attribute__((ext_vector_type(4))) short s16x4;
typedef __bf16 bf16x8 __attribute__((ext_vector_type(8)));
typedef __attribute__((ext_vector_type(4))) float f32x4;

static __device__ inline bf16x8 as_bf16x8(short8 v){ union{short8 s; bf16x8 b;} u; u.s=v; return u.b; }
static __device__ inline short f2bf(float x){ __hip_bfloat16 h = __float2bfloat16(x); return *(short*)&h; }
static __device__ inline float bf2f(short s){ return __uint_as_float(((unsigned)(unsigned short)s)<<16); }

// async global->LDS, 16B per lane; LDS dest = wave-uniform base + lane*16 (linear)
static __device__ inline void gld16(const short* g, short* l){
  __builtin_amdgcn_global_load_lds(
      (const __attribute__((address_space(1))) unsigned int*)g,
      (__attribute__((address_space(3))) unsigned int*)l, 16, 0, 0);
}

// ---------------- stable argsort: LSD radix, 4x8-bit ----------------
__global__ void k_make_keys(const float* __restrict__ inp, unsigned* __restrict__ kA,
                            unsigned* __restrict__ vA){
  unsigned t = blockIdx.x*256u + threadIdx.x;
  unsigned s = t >> 17, i = t & (NPOS-1u);
  unsigned b = s >> 1, ch = 3u + (s & 1u);
  float x = inp[((size_t)b*NPOS + i)*NF + ch];
  unsigned u = __float_as_uint(x);
  u = (u & 0x80000000u) ? ~u : (u | 0x80000000u);
  kA[t] = u; vA[t] = i;
}

__global__ __launch_bounds__(256) void k_hist(const unsigned* __restrict__ src,
                                              unsigned* __restrict__ hist, int shift){
  __shared__ unsigned h[256];
  int tid = threadIdx.x;
  h[tid] = 0u; __syncthreads();
  int s = blockIdx.x / TPS, tile = blockIdx.x % TPS;
  const unsigned* ks = src + (size_t)s*NPOS + (size_t)tile*TILE;
  for (int r = 0; r < TILE/256; ++r){
    unsigned d = (ks[r*256 + tid] >> shift) & 255u;
    atomicAdd(&h[d], 1u);
  }
  __syncthreads();
  hist[s*16384 + tid*TPS + tile] = h[tid];
}

__global__ __launch_bounds__(256) void k_scan(unsigned* __restrict__ hist){
  __shared__ unsigned tot[256];
  int tid = threadIdx.x; int s = blockIdx.x;
  unsigned* g = hist + s*16384;
  unsigned sum = 0;
  for (int q = 0; q < TPS; ++q) sum += g[tid*TPS + q];
  tot[tid] = sum;
  __syncthreads();
  if (tid == 0){
    unsigned run = 0;
    for (int t = 0; t < 256; ++t){ unsigned tmp = tot[t]; tot[t] = run; run += tmp; }
  }
  __syncthreads();
  unsigned run = tot[tid];
  for (int q = 0; q < TPS; ++q){ unsigned tmp = g[tid*TPS+q]; g[tid*TPS+q] = run; run += tmp; }
}

__global__ __launch_bounds__(128) void k_scatter(const unsigned* __restrict__ srcK,
    const unsigned* __restrict__ srcV, unsigned* __restrict__ dstK, unsigned* __restrict__ dstV,
    const unsigned* __restrict__ off, int shift){
  __shared__ unsigned short cnt[256*128];
  int tid = threadIdx.x;
  unsigned* cz = (unsigned*)cnt;
  for (int idx = tid; idx < 256*128/2; idx += 128) cz[idx] = 0u;
  __syncthreads();
  int s = blockIdx.x / TPS, tile = blockIdx.x % TPS;
  const unsigned* ks = srcK + (size_t)s*NPOS + (size_t)tile*TILE;
  const unsigned* vs = srcV + (size_t)s*NPOS + (size_t)tile*TILE;
  unsigned k8[EPT], v8[EPT];
  #pragma unroll
  for (int r = 0; r < EPT; ++r){
    k8[r] = ks[tid*EPT + r];
    v8[r] = vs[tid*EPT + r];
    unsigned d = (k8[r] >> shift) & 255u;
    cnt[d*128 + tid]++;
  }
  __syncthreads();
  for (int dd = 0; dd < 2; ++dd){
    int d = tid + dd*128;
    unsigned run = 0;
    for (int t = 0; t < 128; ++t){ unsigned tmp = cnt[d*128 + t]; cnt[d*128 + t] = (unsigned short)run; run += tmp; }
  }
  __syncthreads();
  const unsigned* ob = off + s*16384;
  #pragma unroll
  for (int r = 0; r < EPT; ++r){
    unsigned d = (k8[r] >> shift) & 255u;
    unsigned rk = cnt[d*128 + tid];
    cnt[d*128 + tid] = (unsigned short)(rk + 1u);
    unsigned pos = ob[d*TPS + tile] + rk;
    dstK[(size_t)s*NPOS + pos] = k8[r];
    dstV[(size_t)s*NPOS + pos] = v8[r];
  }
}

// ---------------- bf16 pre-convert: inp row (69 f32) -> inpb row (72 bf16, 16B-aligned) ----
__global__ __launch_bounds__(256) void k_cvt(const float* __restrict__ inp,
                                             short* __restrict__ inpb, int b){
  int t = blockIdx.x*256 + threadIdx.x;   // NPOS*9
  int i = t/9, q = t - i*9;
  const float* sp = inp + ((size_t)b*NPOS + i)*NF + q*8;
  short o[8];
  #pragma unroll
  for (int e = 0; e < 8; ++e){
    int c = q*8 + e;
    o[e] = (c < NF) ? f2bf(sp[e]) : (short)0;
  }
  *(short8*)(inpb + (size_t)i*72 + q*8) = *(short8*)o;
}

// ---------------- gather from L2-resident bf16 rows ----------------
// XA  [224]: [conv0out 0..127][x0 128..196][pad]
// Xcat[288]: layout per XCW comment above
__global__ __launch_bounds__(256) void k_gath2(const short* __restrict__ inpb,
    const unsigned* __restrict__ P1, const unsigned* __restrict__ P0,
    short* __restrict__ XA, short* __restrict__ Xcat){
  int t = blockIdx.x*256 + threadIdx.x;   // NPOS*18
  int i = t/18, u = t - i*18;
  int p = u/9, q = u - p*9;
  if (p){  // x0 rows (sorted by ch4)
    short8 v = *(const short8*)(inpb + (size_t)P1[i]*72 + q*8);
    *(short8*)(XA + (size_t)i*224 + 128 + q*8) = v;
    s16x4 lo = {v[0],v[1],v[2],v[3]}, hi = {v[4],v[5],v[6],v[7]};
    *(s16x4*)(Xcat + (size_t)i*XCW + 132 + q*8) = lo;
    *(s16x4*)(Xcat + (size_t)i*XCW + 136 + q*8) = hi;
  } else {  // g rows (sorted by ch3)
    short8 v = *(const short8*)(inpb + (size_t)P0[i]*72 + q*8);
    *(short8*)(Xcat + (size_t)i*XCW + 208 + q*8) = v;
    if (q == 8){
      s16x4 z4 = {0,0,0,0};
      *(s16x4*)(Xcat + (size_t)i*XCW + 204) = z4;
      short8 z8 = {0,0,0,0,0,0,0,0};
      *(short8*)(Xcat + (size_t)i*XCW + 280) = z8;
    }
  }
}

// ---------------- weight prep: lane-major [wv][q][ksub][ni][lane][8] ----------------
__global__ void k_prepB(const float* __restrict__ w, short* __restrict__ out,
                        int KC, int NQ, int mode, int total){
  int t = blockIdx.x*256 + threadIdx.x;   // one 16B unit (8 weights) per thread
  if (t >= total) return;
  int lane = t & 63, ni = (t>>6) & 1, ksub = (t>>7) & 1;
  int rest = t >> 8;
  int q = rest % NQ;
  int wv = rest / NQ;
  int tap = q / KC, cc = q - tap*KC;
  int nn = wv*32 + ni*16 + (lane & 15);
  int chb = cc*64 + ksub*32 + ((lane >> 4) & 3)*8;
  short o[8];
  #pragma unroll
  for (int e = 0; e < 8; ++e){
    int ch = chb + e;
    float val = 0.f;
    if (mode == 0){ if (ch < 69)  val = w[((size_t)tap*69  + ch)*128 + nn]; }
    else if (mode == 1){
      if (ch < 128)      val = w[((size_t)tap*197 + 69 + ch)*128 + nn];
      else if (ch < 197) val = w[((size_t)tap*197 + ch - 128)*128 + nn];
    }
    else if (mode == 2){ if (ch < 128) val = w[((size_t)tap*128 + ch)*128 + nn]; }
    else {
      int tm = ch / XCW, cm = ch - tm*XCW;
      int orig = -1;
      if (cm < 128)                     orig = 73 + cm;      // conv1out
      else if (cm < 201)                orig = cm - 128;      // F(0..3) + x0(4..72)
      else if (cm >= 208 && cm < 277)   orig = cm - 7;        // g: 201..269
      if (orig >= 0) val = w[((size_t)tm*270 + orig)*128 + nn];
    }
    o[e] = f2bf(val);
  }
  *(short8*)(out + (size_t)t*8) = *(short8*)o;
}

__global__ void k_prepWf(const float* __restrict__ wf, float* __restrict__ out){
  int t = blockIdx.x*256 + threadIdx.x;   // XCW*4
  if (t >= XCW*4) return;
  int c = t >> 2, q = t & 3;
  float v = 0.f;
  if (c < 128)                  v = wf[(69 + c)*4 + q];
  else if (c >= 132 && c < 201) v = wf[(c - 132)*4 + q];
  else if (c >= 208 && c < 277) v = wf[(197 + c - 208)*4 + q];
  out[t] = v;
}

#define OSTR2 136   // bf16 epilogue stride (shorts): 272B rows, 16B-aligned, banks rotate

// ---------------- MFMA conv3: K-split A staging + bf16 OT + B-prefetch ring ----------------
template<int CPAD, int MT>
__global__ __launch_bounds__(256) void k_conv3s(
    const short* __restrict__ src, int sstride, int coff, int cin,
    const short* __restrict__ wB, const float* __restrict__ bias,
    short* __restrict__ dst, int dstride, int n)
{
  constexpr int KC  = CPAD/64;       // total 64-wide chunks
  constexpr int KH  = CPAD/2;        // cols per staged half
  constexpr int KC2 = KH/64;         // chunks per half
  constexpr int SPH = 3*KC2*2;       // steps per half
  constexpr int NST = 2*SPH;         // total steps
  constexpr int PF  = 4;             // B prefetch depth
  constexpr int ASTR = KH + 8;
  constexpr int AG  = KH/8;
  constexpr int MI  = MT/16;
  constexpr size_t ABYTES = (size_t)(MT+2)*ASTR*2;
  constexpr size_t OBYTES = (size_t)MT*OSTR2*2;
  constexpr size_t LBYTES = (ABYTES > OBYTES) ? ABYTES : OBYTES;
  __shared__ __attribute__((aligned(16))) char LDS[LBYTES];
  short* A_s = (short*)LDS;
  short* OTs = (short*)LDS;          // aliases A_s; used after final barrier
  int tid = threadIdx.x;
  int i0 = blockIdx.x*MT;
  int wv = tid >> 6, lane = tid & 63;
  int lm = lane & 15, lk = lane >> 4;

  const short* wBw = wB + (size_t)wv*(KC*6)*1024 + (size_t)lane*8;
  // step ls -> (h, tp, c, ksub); B slot q = tp*KC + h*KC2 + c
  auto LB = [&](int ls, int ni){
    int h = ls / SPH, r1 = ls % SPH;
    int tp = r1 / (KC2*2), r2 = r1 % (KC2*2);
    int c = r2 >> 1, ksub = r2 & 1;
    int q = tp*KC + h*KC2 + c;
    return as_bf16x8(*(const short8*)(wBw + ((q*2 + ksub)*2 + ni)*512));
  };
  auto stageA = [&](int h){
    for (int idx = tid; idx < (MT+2)*AG; idx += 256){
      int r = idx / AG, g = idx - r*AG;
      int pos = i0 - 1 + r;
      int cb = h*KH + g*8;           // col within CPAD
      short8 v = {0,0,0,0,0,0,0,0};
      if (pos >= 0 && pos < n && cb < cin){
        const short* sp = src + (size_t)pos*sstride + coff + cb;
        if (cb + 8 <= cin) v = *(const short8*)sp;
        else { for (int j = 0; cb + j < cin; ++j) v[j] = sp[j]; }
      }
      *(short8*)(A_s + r*ASTR + g*8) = v;
    }
  };

  bf16x8 bq[PF][2];
  #pragma unroll
  for (int s = 0; s < PF; ++s){ bq[s][0] = LB(s,0); bq[s][1] = LB(s,1); }
  stageA(0);
  __syncthreads();

  f32x4 acc[MI][2] = {};
  #pragma unroll
  for (int ls = 0; ls < NST; ++ls){
    if (ls == SPH){                  // swap to second K-half
      __syncthreads();
      stageA(1);
      __syncthreads();
    }
    int slot = ls % PF;
    bf16x8 b0 = bq[slot][0], b1 = bq[slot][1];
    if (ls + PF < NST){ bq[slot][0] = LB(ls+PF,0); bq[slot][1] = LB(ls+PF,1); }
    int r1 = ls % SPH;
    int tp = r1 / (KC2*2), r2 = r1 % (KC2*2);
    int c = r2 >> 1, ksub = r2 & 1;
    bf16x8 a[MI];
    #pragma unroll
    for (int mi = 0; mi < MI; ++mi)
      a[mi] = as_bf16x8(*(const short8*)(A_s + (mi*16+lm+tp)*ASTR + c*64 + ksub*32 + lk*8));
    #pragma unroll
    for (int mi = 0; mi < MI; ++mi){
      acc[mi][0] = __builtin_amdgcn_mfma_f32_16x16x32_bf16(a[mi], b0, acc[mi][0], 0, 0, 0);
      acc[mi][1] = __builtin_amdgcn_mfma_f32_16x16x32_bf16(a[mi], b1, acc[mi][1], 0, 0, 0);
    }
  }
  __syncthreads();   // all A_s reads done before OTs (alias) writes
  float b0s = bias[wv*32 + lm], b1s = bias[wv*32 + 16 + lm];
  #pragma unroll
  for (int mi = 0; mi < MI; ++mi)
    #pragma unroll
    for (int ni = 0; ni < 2; ++ni){
      float bb = ni ? b1s : b0s;
      #pragma unroll
      for (int r = 0; r < 4; ++r)
        OTs[(mi*16 + lk*4 + r)*OSTR2 + wv*32 + ni*16 + lm] = f2bf(fmaxf(acc[mi][ni][r] + bb, 0.f));
    }
  __syncthreads();
  {
    constexpr int CPT = (MT*128/8)/256;   // short8 units per thread
    int unit0 = tid*CPT;
    int r = unit0 >> 4, uq = unit0 & 15;
    const short* row = OTs + r*OSTR2 + uq*8;
    short* dp = dst + (size_t)(i0 + r)*dstride + uq*8;
    #pragma unroll
    for (int j = 0; j < CPT; ++j)
      *(short8*)(dp + j*8) = *(const short8*)(row + j*8);
  }
}

// ---------------- MFMA merge: (NMRG x 1152) x (1152 x 128); M=32 tiles, A dbuf, B reg-stream ----
__global__ __launch_bounds__(256) void k_mergem4(const short* __restrict__ Xf,
    const short* __restrict__ wB, const float* __restrict__ bias, short* __restrict__ dst)
{
  constexpr int NS = 4*XCW/64;                    // 18 K-steps
  constexpr size_t ABYTES = 2*2048*2;             // 2 x (32 rows x 64 cols) bf16
  constexpr size_t OBYTES = (size_t)32*OSTR2*2;   // 8704
  constexpr size_t LBYTES = (ABYTES > OBYTES) ? ABYTES : OBYTES;
  __shared__ __attribute__((aligned(16))) char LDS[LBYTES];
  short* A_s = (short*)LDS;
  short* OTs = (short*)LDS;
  int tid = threadIdx.x;
  int j0 = blockIdx.x*32;
  int wv = tid >> 6, lane = tid & 63;
  int lm = lane & 15, lk = lane >> 4;
  auto stageA = [&](int s){
    int r = tid >> 3, kv = tid & 7;               // 256 units: [32 rows][8 chunks]
    const short* gp = Xf + (size_t)(j0 + r)*(4*XCW) + s*64 + ((kv ^ (r&7))*8);
    gld16(gp, A_s + (s&1)*2048 + tid*8);
  };
  const short* wBl = wB + (size_t)wv*NS*2048 + (size_t)lane*8;
  auto LB = [&](int s, int ks, int ni){
    return as_bf16x8(*(const short8*)(wBl + ((size_t)(s*2 + ks)*2 + ni)*512));
  };
  bf16x8 c00 = LB(0,0,0), c01 = LB(0,0,1), c10 = LB(0,1,0), c11 = LB(0,1,1);
  stageA(0);
  __syncthreads();
  f32x4 acc[2][2] = {};
  for (int s = 0; s < NS; ++s){
    bf16x8 n00, n01, n10, n11;
    if (s < NS-1){
      n00 = LB(s+1,0,0); n01 = LB(s+1,0,1); n10 = LB(s+1,1,0); n11 = LB(s+1,1,1);
      stageA(s+1);
    }
    const short* Ab = A_s + (s&1)*2048;
    bf16x8 a[2];
    #pragma unroll
    for (int mi = 0; mi < 2; ++mi){
      int r = mi*16 + lm;
      a[mi] = as_bf16x8(*(const short8*)(Ab + r*64 + ((lk ^ (r&7))*8)));
    }
    #pragma unroll
    for (int mi = 0; mi < 2; ++mi){
      acc[mi][0] = __builtin_amdgcn_mfma_f32_16x16x32_bf16(a[mi], c00, acc[mi][0], 0, 0, 0);
      acc[mi][1] = __builtin_amdgcn_mfma_f32_16x16x32_bf16(a[mi], c01, acc[mi][1], 0, 0, 0);
    }
    #pragma unroll
    for (int mi = 0; mi < 2; ++mi){
      int r = mi*16 + lm;
      a[mi] = as_bf16x8(*(const short8*)(Ab + r*64 + (((4+lk) ^ (r&7))*8)));
    }
    #pragma unroll
    for (int mi = 0; mi < 2; ++mi){
      acc[mi][0] = __builtin_amdgcn_mfma_f32_16x16x32_bf16(a[mi], c10, acc[mi][0], 0, 0, 0);
      acc[mi][1] = __builtin_amdgcn_mfma_f32_16x16x32_bf16(a[mi], c11, acc[mi][1], 0, 0, 0);
    }
    __syncthreads();
    c00 = n00; c01 = n01; c10 = n10; c11 = n11;
  }
  float b0 = bias[wv*32 + lm], b1 = bias[wv*32 + 16 + lm];
  #pragma unroll
  for (int mi = 0; mi < 2; ++mi)
    #pragma unroll
    for (int ni = 0; ni < 2; ++ni){
      float bb = ni ? b1 : b0;
      #pragma unroll
      for (int r = 0; r < 4; ++r)
        OTs[(mi*16 + lk*4 + r)*OSTR2 + wv*32 + ni*16 + lm] = f2bf(fmaxf(acc[mi][ni][r] + bb, 0.f));
    }
  __syncthreads();
  {
    int unit0 = tid*2;                 // 512 units: [32 rows][16 units]
    int r = unit0 >> 4, uq = unit0 & 15;
    const short* row = OTs + r*OSTR2 + uq*8;
    short* dp = dst + (size_t)(j0 + r)*128 + uq*8;
    #pragma unroll
    for (int j = 0; j < 2; ++j)
      *(short8*)(dp + j*8) = *(const short8*)(row + j*8);
  }
}

// ---------------- flags head ----------------
__global__ __launch_bounds__(256) void k_flags2(short* __restrict__ Xcat,
    const float* __restrict__ Wf2, const float* __restrict__ bf, float* __restrict__ F){
  size_t i = (size_t)blockIdx.x*256 + threadIdx.x;
  const short* x = Xcat + i*XCW;
  float a0 = bf[0], a1 = bf[1], a2 = bf[2], a3 = bf[3];
  for (int g = 0; g < XCW/8; ++g){
    short8 x8 = *(const short8*)(x + g*8);
    #pragma unroll
    for (int e = 0; e < 8; ++e){
      float xv = bf2f(x8[e]);
      const float* w = Wf2 + (g*8+e)*4;
      a0 = fmaf(xv,w[0],a0); a1 = fmaf(xv,w[1],a1); a2 = fmaf(xv,w[2],a2); a3 = fmaf(xv,w[3],a3);
    }
  }
  float f0 = 1.f/(1.f+expf(-a0)), f1 = 1.f/(1.f+expf(-a1));
  float f2 = 1.f/(1.f+expf(-a2)), f3 = 1.f/(1.f+expf(-a3));
  float* f = F + i*4;
  f[0]=f0; f[1]=f1; f[2]=f2; f[3]=f3;
  short* xc = Xcat + i*XCW + 128;
  xc[0]=f2bf(f0); xc[1]=f2bf(f1); xc[2]=f2bf(f2); xc[3]=f2bf(f3);
}

// ---------------- output head ----------------
__global__ __launch_bounds__(256) void k_out(const short* __restrict__ S,
    const float* __restrict__ F, const float* __restrict__ Ws, const float* __restrict__ bs,
    float* __restrict__ out, int b){
  size_t j = (size_t)blockIdx.x*256 + threadIdx.x;
  float l[16];
  #pragma unroll
  for (int t = 0; t < 16; ++t) l[t] = bs[t];
  const short* s = S + j*128;
  for (int g = 0; g < 16; ++g){
    short8 x8 = *(const short8*)(s + g*8);
    #pragma unroll
    for (int e = 0; e < 8; ++e){
      float x = bf2f(x8[e]);
      const float* w = Ws + (g*8+e)*16;
      #pragma unroll
      for (int t = 0; t < 16; ++t) l[t] = fmaf(x, w[t], l[t]);
    }
  }
  float m = l[0];
  #pragma unroll
  for (int t = 1; t < 16; ++t) m = fmaxf(m, l[t]);
  float sum = 0.f;
  #pragma unroll
  for (int t = 0; t < 16; ++t){ l[t] = expf(l[t]-m); sum += l[t]; }
  float inv = 1.f/sum;
  float* o = out + ((size_t)b*NMRG + j)*20;
  #pragma unroll
  for (int k = 0; k < 4; ++k){
    size_t r = (size_t)(4*j + k)*4;
    o[k] = F[r] - F[r+1];
  }
  #pragma unroll
  for (int t = 0; t < 16; ++t) o[4+t] = l[t]*inv;
}

extern "C" void kernel_launch(void* const* d_in, const int* in_sizes, int n_in,
                              void* d_out, int out_size, void* d_ws, size_t ws_size,
                              hipStream_t stream){
  const float* inp     = (const float*)d_in[0];
  const float* w_pre0  = (const float*)d_in[1];
  const float* b_pre0  = (const float*)d_in[2];
  const float* w_pre1  = (const float*)d_in[3];
  const float* b_pre1  = (const float*)d_in[4];
  const float* w_flags = (const float*)d_in[5];
  const float* b_flags = (const float*)d_in[6];
  const float* w_merge = (const float*)d_in[7];
  const float* b_merge = (const float*)d_in[8];
  const float* w_post[4] = {(const float*)d_in[9], (const float*)d_in[11],
                            (const float*)d_in[13], (const float*)d_in[15]};
  const float* b_post[4] = {(const float*)d_in[10], (const float*)d_in[12],
                            (const float*)d_in[14], (const float*)d_in[16]};
  const float* w_sym   = (const float*)d_in[17];
  const float* b_sym   = (const float*)d_in[18];
  float* outp = (float*)d_out;

  char* p = (char*)d_ws;
  unsigned* kA = (unsigned*)p; p += (size_t)NSORT*NPOS*4;
  unsigned* vA = (unsigned*)p; p += (size_t)NSORT*NPOS*4;
  unsigned* kB = (unsigned*)p; p += (size_t)NSORT*NPOS*4;
  unsigned* vB = (unsigned*)p; p += (size_t)NSORT*NPOS*4;
  unsigned* hist = (unsigned*)p; p += (size_t)NSORT*16384*4;
  short* inpb = (short*)p; p += (size_t)NPOS*72*2;
  short* XA   = (short*)p; p += (size_t)NPOS*224*2;
  short* Xcat = (short*)p; p += (size_t)NPOS*XCW*2;
  float* Fbuf = (float*)p; p += (size_t)NPOS*4*4;
  short* M0   = (short*)p; p += (size_t)NMRG*128*2;
  short* M1   = (short*)p; p += (size_t)NMRG*128*2;
  short* wb0  = (short*)p; p += (size_t)3*2*8192*2;
  short* wb1  = (short*)p; p += (size_t)3*4*8192*2;
  short* wbq0 = (short*)p; p += (size_t)3*2*8192*2;
  short* wbq1 = (short*)p; p += (size_t)3*2*8192*2;
  short* wbq2 = (short*)p; p += (size_t)3*2*8192*2;
  short* wbq3 = (short*)p; p += (size_t)3*2*8192*2;
  short* wbm  = (short*)p; p += (size_t)18*8192*2;
  float* wf2  = (float*)p; p += (size_t)XCW*4*4;
  if ((size_t)(p - (char*)d_ws) > ws_size) return;
  short* wbq[4] = {wbq0, wbq1, wbq2, wbq3};

  // weight prep (cheap, once per call); lane-major layouts
  k_prepB<<<(6144 +255)/256, 256, 0, stream>>>(w_pre0, wb0, 2, 6, 0, 6144);
  k_prepB<<<(12288+255)/256, 256, 0, stream>>>(w_pre1, wb1, 4, 12, 1, 12288);
  for (int i = 0; i < 4; ++i)
    k_prepB<<<(6144+255)/256, 256, 0, stream>>>(w_post[i], wbq[i], 2, 6, 2, 6144);
  k_prepB<<<(18432+255)/256, 256, 0, stream>>>(w_merge, wbm, 18, 18, 3, 18432);
  k_prepWf<<<(XCW*4+255)/256, 256, 0, stream>>>(w_flags, wf2);

  // sorts
  k_make_keys<<<NSORT*NPOS/256, 256, 0, stream>>>(inp, kA, vA);
  unsigned *sk = kA, *sv = vA, *dk = kB, *dv = vB;
  for (int pass = 0; pass < 4; ++pass){
    int shift = pass*8;
    k_hist<<<NSORT*TPS, 256, 0, stream>>>(sk, hist, shift);
    k_scan<<<NSORT, 256, 0, stream>>>(hist);
    k_scatter<<<NSORT*TPS, 128, 0, stream>>>(sk, sv, dk, dv, hist, shift);
    unsigned* t;
    t = sk; sk = dk; dk = t;
    t = sv; sv = dv; dv = t;
  }
  for (int b = 0; b < 2; ++b){
    const unsigned* P0 = sv + (size_t)(b*2+0)*NPOS;  // argsort of ch 3
    const unsigned* P1 = sv + (size_t)(b*2+1)*NPOS;  // argsort of ch 4
    k_cvt<<<NPOS*9/256, 256, 0, stream>>>(inp, inpb, b);
    k_gath2<<<NPOS*18/256, 256, 0, stream>>>(inpb, P1, P0, XA, Xcat);
    k_conv3s<128,64><<<NPOS/64, 256, 0, stream>>>(XA, 224, 128, 69,  wb0, b_pre0, XA,   224, NPOS);
    k_conv3s<256,64><<<NPOS/64, 256, 0, stream>>>(XA, 224, 0,   197, wb1, b_pre1, Xcat, XCW, NPOS);
    k_flags2<<<NPOS/256, 256, 0, stream>>>(Xcat, wf2, b_flags, Fbuf);
    k_mergem4<<<NMRG/32, 256, 0, stream>>>(Xcat, wbm, b_merge, M0);
    k_conv3s<128,32><<<NMRG/32, 256, 0, stream>>>(M0, 128, 0, 128, wbq[0], b_post[0], M1, 128, NMRG);
    k_conv3s<128,32><<<NMRG/32, 256, 0, stream>>>(M1, 128, 0, 128, wbq[1], b_post[1], M0, 128, NMRG);
    k_conv3s<128,32><<<NMRG/32, 256, 0, stream>>>(M0, 128, 0, 128, wbq[2], b_post[2], M1, 128, NMRG);
    k_conv3s<128,32><<<NMRG/32, 256, 0, stream>>>(M1, 128, 0, 128, wbq[3], b_post[3], M0, 128, NMRG);
    k_out<<<NMRG/256, 256, 0, stream>>>(M0, Fbuf, w_sym, b_sym, outp, b);
  }
}